// Round 1
// baseline (668.145 us; speedup 1.0000x reference)
//
#include <hip/hip_runtime.h>
#include <hip/hip_bf16.h>
#include <math.h>

#define B_    64
#define V_    5023
#define VM_   3500
#define LAT_  556
#define DIN_  150528
#define NS_   400
#define N2_   15069        // V_*3
#define ROWS_ 7079         // per-batch output rows
#define LE0_  3931
#define RE0_  4477
#define NEYE_ 546

// ws layout (float offsets)
#define WS_LATENT 0
#define WS_VERT0  35584
#define WS_VERT   1000000
#define WS_PB     1964416
#define PB_STRIDE 32
// pb per-batch: [0..2] vmean, [3..11] R (row-major R[l*3+i]), [12] scale,
//               [13..15] t, [16..18] left_gaze, [19..21] right_gaze

// ---------------------------------------------------------------- init latent
__global__ void k_init_latent(const float* __restrict__ enc_b,
                              float* __restrict__ latent) {
    int i = blockIdx.x * 256 + threadIdx.x;
    if (i < B_ * LAT_) latent[i] = enc_b[i % LAT_];
}

// ---------------------------------------------------------------- big GEMM
// latent[b][n] += sum_k x[b][k] * W[k][n]; grid (9 n-tiles, 147 k-chunks)
__global__ __launch_bounds__(256) void k_gemm(const float* __restrict__ x,
                                              const float* __restrict__ W,
                                              float* __restrict__ latent) {
    __shared__ float xs[16][64];    // [kk][b]  (transposed for f4 reads)
    __shared__ float wsm[16][64];   // [kk][n]
    const int n0  = blockIdx.x * 64;
    const int k0  = blockIdx.y * 1024;
    const int tid = threadIdx.x;
    const int tb  = tid >> 4;          // 0..15 -> b base tb*4
    const int tn  = tid & 15;          // 0..15 -> n base tn*4
    const int lb  = tid >> 2;          // 0..63  x loader: batch
    const int lk4 = (tid & 3) << 2;    // 0,4,8,12 x loader: kk base
    const int wkk = tid >> 4;          // 0..15  W loader: kk
    const int wn4 = (tid & 15) << 2;   // W loader: n offset
    const int nb  = n0 + wn4;
    const bool wvalid = nb < LAT_;     // LAT_%4==0 -> whole f4 valid or not
    float acc[4][4] = {{0.f,0.f,0.f,0.f},{0.f,0.f,0.f,0.f},
                       {0.f,0.f,0.f,0.f},{0.f,0.f,0.f,0.f}};
    for (int kt = 0; kt < 1024; kt += 16) {
        const int kb = k0 + kt;
        float4 xv = *(const float4*)(x + (size_t)lb * DIN_ + kb + lk4);
        float4 wv = make_float4(0.f, 0.f, 0.f, 0.f);
        if (wvalid) wv = *(const float4*)(W + (size_t)(kb + wkk) * LAT_ + nb);
        __syncthreads();
        xs[lk4 + 0][lb] = xv.x;
        xs[lk4 + 1][lb] = xv.y;
        xs[lk4 + 2][lb] = xv.z;
        xs[lk4 + 3][lb] = xv.w;
        *(float4*)&wsm[wkk][wn4] = wv;
        __syncthreads();
#pragma unroll
        for (int kk = 0; kk < 16; ++kk) {
            float4 av = *(const float4*)&xs[kk][tb << 2];
            float4 bv = *(const float4*)&wsm[kk][tn << 2];
            float a[4] = {av.x, av.y, av.z, av.w};
            float b4[4] = {bv.x, bv.y, bv.z, bv.w};
#pragma unroll
            for (int i = 0; i < 4; ++i)
#pragma unroll
                for (int j = 0; j < 4; ++j)
                    acc[i][j] = fmaf(a[i], b4[j], acc[i][j]);
        }
    }
#pragma unroll
    for (int i = 0; i < 4; ++i) {
        int bbi = (tb << 2) + i;
#pragma unroll
        for (int j = 0; j < 4; ++j) {
            int nn = n0 + (tn << 2) + j;
            if (nn < LAT_) atomicAdd(&latent[bbi * LAT_ + nn], acc[i][j]);
        }
    }
}

// ---------------------------------------------------------------- shape GEMM
// vert0[b][n] = vt[n] + sum_s latent[b][s] * sb[s][n],  n = v*3+c
__global__ __launch_bounds__(256) void k_shape(const float* __restrict__ latent,
                                               const float* __restrict__ sb,
                                               const float* __restrict__ vt,
                                               float* __restrict__ vert0) {
    __shared__ float ps[16][64];    // [ss][b]
    __shared__ float bs[16][64];    // [ss][n]
    const int n0  = blockIdx.x * 64;
    const int tid = threadIdx.x;
    const int tb  = tid >> 4;
    const int tn  = tid & 15;
    const int lb  = tid >> 2;
    const int ls4 = (tid & 3) << 2;
    const int wss = tid >> 4;
    const int wn4 = (tid & 15) << 2;
    float acc[4][4];
#pragma unroll
    for (int j = 0; j < 4; ++j) {
        int nn = n0 + (tn << 2) + j;
        float v = (nn < N2_) ? vt[nn] : 0.f;
#pragma unroll
        for (int i = 0; i < 4; ++i) acc[i][j] = v;
    }
    for (int st = 0; st < NS_; st += 16) {
        float4 pv = *(const float4*)(latent + lb * LAT_ + st + ls4);
        float wv[4];
#pragma unroll
        for (int j = 0; j < 4; ++j) {
            int nn = n0 + wn4 + j;
            wv[j] = (nn < N2_) ? sb[(size_t)(st + wss) * N2_ + nn] : 0.f;
        }
        __syncthreads();
        ps[ls4 + 0][lb] = pv.x;
        ps[ls4 + 1][lb] = pv.y;
        ps[ls4 + 2][lb] = pv.z;
        ps[ls4 + 3][lb] = pv.w;
#pragma unroll
        for (int j = 0; j < 4; ++j) bs[wss][wn4 + j] = wv[j];
        __syncthreads();
#pragma unroll
        for (int ss = 0; ss < 16; ++ss) {
            float4 av = *(const float4*)&ps[ss][tb << 2];
            float4 bv = *(const float4*)&bs[ss][tn << 2];
            float a[4] = {av.x, av.y, av.z, av.w};
            float b4[4] = {bv.x, bv.y, bv.z, bv.w};
#pragma unroll
            for (int i = 0; i < 4; ++i)
#pragma unroll
                for (int j = 0; j < 4; ++j)
                    acc[i][j] = fmaf(a[i], b4[j], acc[i][j]);
        }
    }
#pragma unroll
    for (int i = 0; i < 4; ++i) {
#pragma unroll
        for (int j = 0; j < 4; ++j) {
            int nn = n0 + (tn << 2) + j;
            if (nn < N2_) vert0[(size_t)((tb << 2) + i) * N2_ + nn] = acc[i][j];
        }
    }
}

// ---------------------------------------------------------------- helpers
__device__ inline void axis_angle(const float aa0, const float aa1, const float aa2,
                                  float R[9]) {
    float th  = sqrtf(aa0 * aa0 + aa1 * aa1 + aa2 * aa2);
    float inv = 1.0f / fmaxf(th, 1e-8f);
    float v0 = aa0 * inv, v1 = aa1 * inv, v2 = aa2 * inv;
    float s = sinf(th), c = cosf(th);
    float K[9] = {0.f, -v2, v1, v2, 0.f, -v0, -v1, v0, 0.f};
    float KK[9];
#pragma unroll
    for (int i = 0; i < 3; ++i)
#pragma unroll
        for (int j = 0; j < 3; ++j)
            KK[i * 3 + j] = K[i * 3 + 0] * K[0 * 3 + j] +
                            K[i * 3 + 1] * K[1 * 3 + j] +
                            K[i * 3 + 2] * K[2 * 3 + j];
    float omc = 1.0f - c;
#pragma unroll
    for (int i = 0; i < 9; ++i) R[i] = s * K[i] + omc * KK[i];
    R[0] += 1.f; R[4] += 1.f; R[8] += 1.f;
}

// ---------------------------------------------------------------- per-batch stats
// vmean over V, face rotation matrix/scale/t, gaze vectors from l_rot/r_rot
__global__ __launch_bounds__(256) void k_stats(const float* __restrict__ vert0,
                                               const float* __restrict__ latent,
                                               float* __restrict__ pb) {
    const int b   = blockIdx.x;
    const int tid = threadIdx.x;
    __shared__ float red[3][256];
    float s0 = 0.f, s1 = 0.f, s2 = 0.f;
    const float* row = vert0 + (size_t)b * N2_;
    for (int i = tid; i < N2_; i += 256) {
        float v = row[i];
        int c = i % 3;
        if (c == 0) s0 += v; else if (c == 1) s1 += v; else s2 += v;
    }
    red[0][tid] = s0; red[1][tid] = s1; red[2][tid] = s2;
    __syncthreads();
    for (int off = 128; off > 0; off >>= 1) {
        if (tid < off) {
            red[0][tid] += red[0][tid + off];
            red[1][tid] += red[1][tid + off];
            red[2][tid] += red[2][tid + off];
        }
        __syncthreads();
    }
    if (tid == 0) {
        float* p = pb + b * PB_STRIDE;
        p[0] = red[0][0] / (float)V_;
        p[1] = red[1][0] / (float)V_;
        p[2] = red[2][0] / (float)V_;
        const float* lat = latent + b * LAT_;
        float R[9];
        axis_angle(lat[545], lat[546], lat[547], R);
#pragma unroll
        for (int i = 0; i < 9; ++i) p[3 + i] = R[i];
        p[12] = lat[551] + 1.0f;
        p[13] = lat[548]; p[14] = lat[549]; p[15] = lat[550];
        float Rl[9], Rr[9];
        axis_angle(lat[552], lat[553], 0.f, Rl);
        axis_angle(lat[554], lat[555], 0.f, Rr);
        // left/right gaze = (0,0,-1) @ R  = -R[2][:]
        p[16] = -Rl[6]; p[17] = -Rl[7]; p[18] = -Rl[8];
        p[19] = -Rr[6]; p[20] = -Rr[7]; p[21] = -Rr[8];
    }
}

// ---------------------------------------------------------------- transform + project
__global__ __launch_bounds__(256) void k_transform(const float* __restrict__ vert0,
                                                   const float* __restrict__ pb,
                                                   const float* __restrict__ cam,
                                                   float* __restrict__ vert,
                                                   float* __restrict__ out) {
    const int b = blockIdx.y;
    const int v = blockIdx.x * 256 + threadIdx.x;
    if (v >= V_) return;
    const float* p = pb + b * PB_STRIDE;
    const size_t vo = (size_t)b * N2_ + (size_t)v * 3;
    float w0 = vert0[vo + 0] - p[0];
    float w1 = vert0[vo + 1] - p[1];
    float w2 = vert0[vo + 2] - p[2];
    float sc = p[12];
    // out_i = sum_l w_l * R[l][i]; R row-major at p[3..11]
    float r0 = (w0 * p[3] + w1 * p[6] + w2 * p[9])  * sc + p[13];
    float r1 = (w0 * p[4] + w1 * p[7] + w2 * p[10]) * sc + p[14];
    float r2 = (w0 * p[5] + w1 * p[8] + w2 * p[11]) * sc + p[15];
    vert[vo + 0] = r0; vert[vo + 1] = r1; vert[vo + 2] = r2;
    if (v < VM_) {
        size_t o = ((size_t)b * ROWS_ + v) * 3;
        out[o + 0] = r0; out[o + 1] = r1; out[o + 2] = r2;
        const float* cb = cam + b * 12;
        float p0 = cb[0] * r0 + cb[1] * r1 + cb[2]  * r2 + cb[3];
        float p1 = cb[4] * r0 + cb[5] * r1 + cb[6]  * r2 + cb[7];
        float p2 = cb[8] * r0 + cb[9] * r1 + cb[10] * r2 + cb[11];
        float zs = (p2 >= 0.f ? 1.f : -1.f) * fmaxf(fabsf(p2), 0.001f);
        size_t o2 = ((size_t)b * ROWS_ + VM_ + v) * 3;
        out[o2 + 0] = p0 / zs; out[o2 + 1] = p1 / zs; out[o2 + 2] = p2;
    }
}

// ---------------------------------------------------------------- per-batch finale
__global__ __launch_bounds__(256) void k_final(const float* __restrict__ vert,
                                               const float* __restrict__ pb,
                                               const int* __restrict__ lmk,
                                               const int* __restrict__ mlmk,
                                               float* __restrict__ out) {
    const int b   = blockIdx.x;
    const int tid = threadIdx.x;
    __shared__ float red[6][256];
    const float* row = vert + (size_t)b * N2_;
    float l0 = 0.f, l1 = 0.f, l2 = 0.f, r0 = 0.f, r1 = 0.f, r2 = 0.f;
    for (int i = tid; i < 2 * NEYE_ * 3; i += 256) {
        float v = row[LE0_ * 3 + i];
        int c = i % 3;           // LE0_*3 is a multiple of 3
        if (i < NEYE_ * 3) {
            if (c == 0) l0 += v; else if (c == 1) l1 += v; else l2 += v;
        } else {
            if (c == 0) r0 += v; else if (c == 1) r1 += v; else r2 += v;
        }
    }
    red[0][tid] = l0; red[1][tid] = l1; red[2][tid] = l2;
    red[3][tid] = r0; red[4][tid] = r1; red[5][tid] = r2;
    __syncthreads();
    for (int off = 128; off > 0; off >>= 1) {
        if (tid < off) {
#pragma unroll
            for (int q = 0; q < 6; ++q) red[q][tid] += red[q][tid + off];
        }
        __syncthreads();
    }
    // fl3d gather (landmarks are < VM_, rows of vert == rows of vmk)
    if (tid < 204) {
        int j = tid / 3, c = tid % 3;
        int vi = mlmk[j];
        out[((size_t)b * ROWS_ + 7000 + j) * 3 + c] = row[(size_t)vi * 3 + c];
    }
    if (tid == 0) {
        float lc[3], rc[3];
        const float invn = 1.0f / (float)NEYE_;
#pragma unroll
        for (int c = 0; c < 3; ++c) { lc[c] = red[c][0] * invn; rc[c] = red[3 + c][0] * invn; }
        // face centre
        int i4a = lmk[19], i4b = lmk[22], i4c = lmk[25], i4d = lmk[28];
        int i2a = lmk[14], i2b = lmk[18];
        float fc[3];
#pragma unroll
        for (int c = 0; c < 3; ++c) {
            float m4 = (row[i4a * 3 + c] + row[i4b * 3 + c] +
                        row[i4c * 3 + c] + row[i4d * 3 + c]) * 0.25f;
            float m2 = (row[i2a * 3 + c] + row[i2b * 3 + c]) * 0.5f;
            fc[c] = (m4 + m2) * 0.5f;
        }
        const float* p = pb + b * PB_STRIDE;
        float lg[3] = {p[16], p[17], p[18]};
        float rg[3] = {p[19], p[20], p[21]};
        float cr[3] = {rg[1] * lg[2] - rg[2] * lg[1],
                       rg[2] * lg[0] - rg[0] * lg[2],
                       rg[0] * lg[1] - rg[1] * lg[0]};
        float A[3][3], rhs[3];
#pragma unroll
        for (int i = 0; i < 3; ++i) {
            A[i][0] = lg[i]; A[i][1] = -rg[i]; A[i][2] = cr[i];
            rhs[i] = rc[i] - lc[i];
        }
        // 3x3 Gaussian elimination with partial pivoting
        for (int k = 0; k < 3; ++k) {
            int mrow = k; float mv = fabsf(A[k][k]);
            for (int i = k + 1; i < 3; ++i) {
                float av = fabsf(A[i][k]);
                if (av > mv) { mv = av; mrow = i; }
            }
            if (mrow != k) {
                for (int j = 0; j < 3; ++j) { float t = A[k][j]; A[k][j] = A[mrow][j]; A[mrow][j] = t; }
                float t = rhs[k]; rhs[k] = rhs[mrow]; rhs[mrow] = t;
            }
            float inv = 1.0f / A[k][k];
            for (int i = k + 1; i < 3; ++i) {
                float f = A[i][k] * inv;
                for (int j = k; j < 3; ++j) A[i][j] -= f * A[k][j];
                rhs[i] -= f * rhs[k];
            }
        }
        float sol2 = rhs[2] / A[2][2];
        float sol1 = (rhs[1] - A[1][2] * sol2) / A[1][1];
        float sol0 = (rhs[0] - A[0][1] * sol1 - A[0][2] * sol2) / A[0][0];
        float gpl[3], gpr[3], gpm[3];
#pragma unroll
        for (int c = 0; c < 3; ++c) {
            gpl[c] = lc[c] + sol0 * lg[c];
            gpr[c] = rc[c] + sol1 * rg[c];
            gpm[c] = (gpl[c] + gpr[c]) * 0.5f;
        }
        float d0 = gpl[0] - gpr[0], d1 = gpl[1] - gpr[1], d2 = gpl[2] - gpr[2];
        float dist = sqrtf(d0 * d0 + d1 * d1 + d2 * d2);
        float* o = out + ((size_t)b * ROWS_ + 7068) * 3;
#pragma unroll
        for (int c = 0; c < 3; ++c) {
            o[0 * 3 + c]  = lc[c];
            o[1 * 3 + c]  = rc[c];
            o[2 * 3 + c]  = fc[c];
            o[3 * 3 + c]  = gpl[c];
            o[4 * 3 + c]  = gpr[c];
            o[5 * 3 + c]  = gpm[c];
            o[6 * 3 + c]  = lc[c] + lg[c] * 1000.0f;
            o[7 * 3 + c]  = rc[c] + rg[c] * 1000.0f;
            o[8 * 3 + c]  = lg[c];
            o[9 * 3 + c]  = rg[c];
            o[10 * 3 + c] = dist;
        }
    }
}

// ---------------------------------------------------------------- launcher
extern "C" void kernel_launch(void* const* d_in, const int* in_sizes, int n_in,
                              void* d_out, int out_size, void* d_ws, size_t ws_size,
                              hipStream_t stream) {
    const float* x    = (const float*)d_in[0];
    const float* W    = (const float*)d_in[1];
    const float* eb   = (const float*)d_in[2];
    const float* vt   = (const float*)d_in[3];
    const float* sb   = (const float*)d_in[4];
    const float* cam  = (const float*)d_in[5];
    const int*   lmk  = (const int*)d_in[6];
    const int*   mlmk = (const int*)d_in[7];
    float* out = (float*)d_out;
    float* ws  = (float*)d_ws;
    float* latent = ws + WS_LATENT;
    float* vert0  = ws + WS_VERT0;
    float* vert   = ws + WS_VERT;
    float* pb     = ws + WS_PB;

    k_init_latent<<<139, 256, 0, stream>>>(eb, latent);
    k_gemm<<<dim3(9, 147), 256, 0, stream>>>(x, W, latent);
    k_shape<<<236, 256, 0, stream>>>(latent, sb, vt, vert0);
    k_stats<<<64, 256, 0, stream>>>(vert0, latent, pb);
    k_transform<<<dim3(20, 64), 256, 0, stream>>>(vert0, pb, cam, vert, out);
    k_final<<<64, 256, 0, stream>>>(vert, pb, lmk, mlmk, out);
}

// Round 3
// 599.982 us; speedup vs baseline: 1.1136x; 1.1136x over previous
//
#include <hip/hip_runtime.h>
#include <hip/hip_bf16.h>
#include <math.h>

#define B_    64
#define V_    5023
#define VM_   3500
#define LAT_  556
#define DIN_  150528
#define NS_   400
#define N2_   15069        // V_*3
#define ROWS_ 7079         // per-batch output rows
#define LE0_  3931
#define NEYE_ 546

#define KC_   1024         // K per block (147 chunks)
#define KS_   32           // K per subchunk (one MFMA k-step)
#define NSUB_ (KC_/KS_)
#define SDW_  18           // Wt row stride in dwords (36 f16: 32 + pad 4)
#define XSC_  64.0f
#define WSC_  4096.0f
#define OSC_  (1.0f/262144.0f)   // 2^-18

// ws layout (float offsets)
#define WS_LATENT 0
#define WS_VERT0  35584
#define WS_VERT   1000000
#define WS_PB     1964416
#define PB_STRIDE 32

typedef _Float16 f16x8 __attribute__((ext_vector_type(8)));
typedef float    f32x4 __attribute__((ext_vector_type(4)));

union F16x8 { f16x8 v; unsigned int u[4]; _Float16 h[8]; };

static __device__ inline unsigned int packh(_Float16 a, _Float16 b) {
    union { _Float16 h; unsigned short u; } ca, cb;
    ca.h = a; cb.h = b;
    return (unsigned int)ca.u | ((unsigned int)cb.u << 16);
}

// ---------------------------------------------------------------- init latent
__global__ void k_init_latent(const float* __restrict__ enc_b,
                              float* __restrict__ latent) {
    int i = blockIdx.x * 256 + threadIdx.x;
    if (i < B_ * LAT_) latent[i] = enc_b[i % LAT_];
}

// ---------------------------------------------------------------- big GEMM (MFMA f16-split)
// latent[b][n] += sum_k x[b][k] * W[k][n]
// grid (9 n-tiles x 147 k-chunks), 256 threads = 4 waves in 2x2.
// Precision: x = xhi + xlo, W = whi + wlo in f16 (scaled); 3 MFMA terms.
__global__ __launch_bounds__(256) void k_gemm(const float* __restrict__ x,
                                              const float* __restrict__ W,
                                              float* __restrict__ latent) {
    // Wt[dbuf][hi/lo][n_local*SDW_ + k/2] : k-pair packed per dword, [n][k] layout
    __shared__ __align__(16) unsigned int wt[2][2][64 * SDW_];
    const int tid = threadIdx.x;
    const int n0  = blockIdx.x * 64;
    const int k0  = blockIdx.y * KC_;
    // staging map: thread handles k-pair (2*skp, 2*skp+1) x 4 cols
    const int sq   = tid & 15;          // col quad -> cols 4sq..4sq+3
    const int skp  = tid >> 4;          // k-pair index 0..15
    const int scol = n0 + sq * 4;
    const bool svalid = scol < LAT_;    // LAT_ % 4 == 0: quad fully valid or fully OOB
    // wave / fragment map: wave w in 2x2 (wr = rows half, wc = cols half)
    const int lane = tid & 63;
    const int w    = tid >> 6;
    const int wr   = w >> 1;
    const int wc   = w & 1;
    const int c16  = lane & 15;
    const int g    = lane >> 4;

    f32x4 acc[2][2] = {};
    float4 wv0, wv1;
    {   // prologue: load W tile for s=0
        const float* wp = W + (size_t)(k0 + 2 * skp) * LAT_ + scol;
        wv0 = svalid ? *(const float4*)wp : make_float4(0.f, 0.f, 0.f, 0.f);
        wv1 = svalid ? *(const float4*)(wp + LAT_) : make_float4(0.f, 0.f, 0.f, 0.f);
    }
    for (int s = 0; s < NSUB_; ++s) {
        const int db = s & 1;
        {   // convert + transpose-write current W tile into LDS
            float v0[4] = {wv0.x, wv0.y, wv0.z, wv0.w};
            float v1[4] = {wv1.x, wv1.y, wv1.z, wv1.w};
#pragma unroll
            for (int c = 0; c < 4; ++c) {
                float a = v0[c] * WSC_, b = v1[c] * WSC_;
                _Float16 h0 = (_Float16)a, h1 = (_Float16)b;
                _Float16 l0 = (_Float16)(a - (float)h0);
                _Float16 l1 = (_Float16)(b - (float)h1);
                wt[db][0][(sq * 4 + c) * SDW_ + skp] = packh(h0, h1);
                wt[db][1][(sq * 4 + c) * SDW_ + skp] = packh(l0, l1);
            }
        }
        if (s + 1 < NSUB_) {   // prefetch next W tile (in flight during MFMA)
            const float* wp = W + (size_t)(k0 + (s + 1) * KS_ + 2 * skp) * LAT_ + scol;
            wv0 = svalid ? *(const float4*)wp : make_float4(0.f, 0.f, 0.f, 0.f);
            wv1 = svalid ? *(const float4*)(wp + LAT_) : make_float4(0.f, 0.f, 0.f, 0.f);
        }
        __syncthreads();   // wt[db] ready; prior-iter reads of wt[db^1] all drained
        // A fragments straight from global (x is L2/L3-resident)
        F16x8 ahi[2], alo[2];
#pragma unroll
        for (int rf = 0; rf < 2; ++rf) {
            const int row = 32 * wr + 16 * rf + c16;
            const float* xp = x + (size_t)row * DIN_ + k0 + s * KS_ + 8 * g;
            float4 a0 = *(const float4*)xp;
            float4 a1 = *(const float4*)(xp + 4);
            float av[8] = {a0.x, a0.y, a0.z, a0.w, a1.x, a1.y, a1.z, a1.w};
#pragma unroll
            for (int j = 0; j < 8; ++j) {
                float sv = av[j] * XSC_;
                _Float16 h = (_Float16)sv;
                ahi[rf].h[j] = h;
                alo[rf].h[j] = (_Float16)(sv - (float)h);
            }
        }
        // B fragments from LDS + 12 MFMA
#pragma unroll
        for (int cf = 0; cf < 2; ++cf) {
            const int nl = 32 * wc + 16 * cf + c16;
            const unsigned int* ph = &wt[db][0][nl * SDW_ + 4 * g];
            const unsigned int* pl = &wt[db][1][nl * SDW_ + 4 * g];
            F16x8 bh, bl;
            uint2 t0 = *(const uint2*)ph;
            uint2 t1 = *(const uint2*)(ph + 2);
            bh.u[0] = t0.x; bh.u[1] = t0.y; bh.u[2] = t1.x; bh.u[3] = t1.y;
            uint2 u0 = *(const uint2*)pl;
            uint2 u1 = *(const uint2*)(pl + 2);
            bl.u[0] = u0.x; bl.u[1] = u0.y; bl.u[2] = u1.x; bl.u[3] = u1.y;
#pragma unroll
            for (int rf = 0; rf < 2; ++rf) {
                acc[rf][cf] = __builtin_amdgcn_mfma_f32_16x16x32_f16(ahi[rf].v, bh.v, acc[rf][cf], 0, 0, 0);
                acc[rf][cf] = __builtin_amdgcn_mfma_f32_16x16x32_f16(ahi[rf].v, bl.v, acc[rf][cf], 0, 0, 0);
                acc[rf][cf] = __builtin_amdgcn_mfma_f32_16x16x32_f16(alo[rf].v, bh.v, acc[rf][cf], 0, 0, 0);
            }
        }
        // no second barrier needed: next iter writes wt[db^1], and this iter's
        // LDS reads are drained by the lgkmcnt(0) before next iter's barrier.
    }
    // epilogue: C/D layout col=lane&15, row=(lane>>4)*4+i
#pragma unroll
    for (int rf = 0; rf < 2; ++rf)
#pragma unroll
        for (int cf = 0; cf < 2; ++cf)
#pragma unroll
            for (int i = 0; i < 4; ++i) {
                int row = 32 * wr + 16 * rf + 4 * g + i;   // batch
                int col = n0 + 32 * wc + 16 * cf + c16;    // n
                if (col < LAT_)
                    atomicAdd(&latent[row * LAT_ + col], acc[rf][cf][i] * OSC_);
            }
}

// ---------------------------------------------------------------- shape GEMM
// vert0[b][n] = vt[n] + sum_s latent[b][s] * sb[s][n],  n = v*3+c
__global__ __launch_bounds__(256) void k_shape(const float* __restrict__ latent,
                                               const float* __restrict__ sb,
                                               const float* __restrict__ vt,
                                               float* __restrict__ vert0) {
    __shared__ float ps[16][64];    // [ss][b]
    __shared__ float bs[16][64];    // [ss][n]
    const int n0  = blockIdx.x * 64;
    const int tid = threadIdx.x;
    const int tb  = tid >> 4;
    const int tn  = tid & 15;
    const int lb  = tid >> 2;
    const int ls4 = (tid & 3) << 2;
    const int wss = tid >> 4;
    const int wn4 = (tid & 15) << 2;
    float acc[4][4];
#pragma unroll
    for (int j = 0; j < 4; ++j) {
        int nn = n0 + (tn << 2) + j;
        float v = (nn < N2_) ? vt[nn] : 0.f;
#pragma unroll
        for (int i = 0; i < 4; ++i) acc[i][j] = v;
    }
    for (int st = 0; st < NS_; st += 16) {
        float4 pv = *(const float4*)(latent + lb * LAT_ + st + ls4);
        float wv[4];
        int nn0 = n0 + wn4;
        if (nn0 + 3 < N2_) {
            float4 t = *(const float4*)(sb + (size_t)(st + wss) * N2_ + nn0);
            wv[0] = t.x; wv[1] = t.y; wv[2] = t.z; wv[3] = t.w;
        } else {
#pragma unroll
            for (int j = 0; j < 4; ++j) {
                int nn = nn0 + j;
                wv[j] = (nn < N2_) ? sb[(size_t)(st + wss) * N2_ + nn] : 0.f;
            }
        }
        __syncthreads();
        ps[ls4 + 0][lb] = pv.x;
        ps[ls4 + 1][lb] = pv.y;
        ps[ls4 + 2][lb] = pv.z;
        ps[ls4 + 3][lb] = pv.w;
#pragma unroll
        for (int j = 0; j < 4; ++j) bs[wss][wn4 + j] = wv[j];
        __syncthreads();
#pragma unroll
        for (int ss = 0; ss < 16; ++ss) {
            float4 av = *(const float4*)&ps[ss][tb << 2];
            float4 bv = *(const float4*)&bs[ss][tn << 2];
            float a[4] = {av.x, av.y, av.z, av.w};
            float b4[4] = {bv.x, bv.y, bv.z, bv.w};
#pragma unroll
            for (int i = 0; i < 4; ++i)
#pragma unroll
                for (int j = 0; j < 4; ++j)
                    acc[i][j] = fmaf(a[i], b4[j], acc[i][j]);
        }
    }
#pragma unroll
    for (int i = 0; i < 4; ++i) {
#pragma unroll
        for (int j = 0; j < 4; ++j) {
            int nn = n0 + (tn << 2) + j;
            if (nn < N2_) vert0[(size_t)((tb << 2) + i) * N2_ + nn] = acc[i][j];
        }
    }
}

// ---------------------------------------------------------------- helpers
__device__ inline void axis_angle(const float aa0, const float aa1, const float aa2,
                                  float R[9]) {
    float th  = sqrtf(aa0 * aa0 + aa1 * aa1 + aa2 * aa2);
    float inv = 1.0f / fmaxf(th, 1e-8f);
    float v0 = aa0 * inv, v1 = aa1 * inv, v2 = aa2 * inv;
    float s = sinf(th), c = cosf(th);
    float K[9] = {0.f, -v2, v1, v2, 0.f, -v0, -v1, v0, 0.f};
    float KK[9];
#pragma unroll
    for (int i = 0; i < 3; ++i)
#pragma unroll
        for (int j = 0; j < 3; ++j)
            KK[i * 3 + j] = K[i * 3 + 0] * K[0 * 3 + j] +
                            K[i * 3 + 1] * K[1 * 3 + j] +
                            K[i * 3 + 2] * K[2 * 3 + j];
    float omc = 1.0f - c;
#pragma unroll
    for (int i = 0; i < 9; ++i) R[i] = s * K[i] + omc * KK[i];
    R[0] += 1.f; R[4] += 1.f; R[8] += 1.f;
}

// ---------------------------------------------------------------- per-batch stats
__global__ __launch_bounds__(256) void k_stats(const float* __restrict__ vert0,
                                               const float* __restrict__ latent,
                                               float* __restrict__ pb) {
    const int b   = blockIdx.x;
    const int tid = threadIdx.x;
    __shared__ float red[3][256];
    float s0 = 0.f, s1 = 0.f, s2 = 0.f;
    const float* row = vert0 + (size_t)b * N2_;
    for (int i = tid; i < N2_; i += 256) {
        float v = row[i];
        int c = i % 3;
        if (c == 0) s0 += v; else if (c == 1) s1 += v; else s2 += v;
    }
    red[0][tid] = s0; red[1][tid] = s1; red[2][tid] = s2;
    __syncthreads();
    for (int off = 128; off > 0; off >>= 1) {
        if (tid < off) {
            red[0][tid] += red[0][tid + off];
            red[1][tid] += red[1][tid + off];
            red[2][tid] += red[2][tid + off];
        }
        __syncthreads();
    }
    if (tid == 0) {
        float* p = pb + b * PB_STRIDE;
        p[0] = red[0][0] / (float)V_;
        p[1] = red[1][0] / (float)V_;
        p[2] = red[2][0] / (float)V_;
        const float* lat = latent + b * LAT_;
        float R[9];
        axis_angle(lat[545], lat[546], lat[547], R);
#pragma unroll
        for (int i = 0; i < 9; ++i) p[3 + i] = R[i];
        p[12] = lat[551] + 1.0f;
        p[13] = lat[548]; p[14] = lat[549]; p[15] = lat[550];
        float Rl[9], Rr[9];
        axis_angle(lat[552], lat[553], 0.f, Rl);
        axis_angle(lat[554], lat[555], 0.f, Rr);
        p[16] = -Rl[6]; p[17] = -Rl[7]; p[18] = -Rl[8];
        p[19] = -Rr[6]; p[20] = -Rr[7]; p[21] = -Rr[8];
    }
}

// ---------------------------------------------------------------- transform + project
__global__ __launch_bounds__(256) void k_transform(const float* __restrict__ vert0,
                                                   const float* __restrict__ pb,
                                                   const float* __restrict__ cam,
                                                   float* __restrict__ vert,
                                                   float* __restrict__ out) {
    const int b = blockIdx.y;
    const int v = blockIdx.x * 256 + threadIdx.x;
    if (v >= V_) return;
    const float* p = pb + b * PB_STRIDE;
    const size_t vo = (size_t)b * N2_ + (size_t)v * 3;
    float w0 = vert0[vo + 0] - p[0];
    float w1 = vert0[vo + 1] - p[1];
    float w2 = vert0[vo + 2] - p[2];
    float sc = p[12];
    float r0 = (w0 * p[3] + w1 * p[6] + w2 * p[9])  * sc + p[13];
    float r1 = (w0 * p[4] + w1 * p[7] + w2 * p[10]) * sc + p[14];
    float r2 = (w0 * p[5] + w1 * p[8] + w2 * p[11]) * sc + p[15];
    vert[vo + 0] = r0; vert[vo + 1] = r1; vert[vo + 2] = r2;
    if (v < VM_) {
        size_t o = ((size_t)b * ROWS_ + v) * 3;
        out[o + 0] = r0; out[o + 1] = r1; out[o + 2] = r2;
        const float* cb = cam + b * 12;
        float p0 = cb[0] * r0 + cb[1] * r1 + cb[2]  * r2 + cb[3];
        float p1 = cb[4] * r0 + cb[5] * r1 + cb[6]  * r2 + cb[7];
        float p2 = cb[8] * r0 + cb[9] * r1 + cb[10] * r2 + cb[11];
        float zs = (p2 >= 0.f ? 1.f : -1.f) * fmaxf(fabsf(p2), 0.001f);
        size_t o2 = ((size_t)b * ROWS_ + VM_ + v) * 3;
        out[o2 + 0] = p0 / zs; out[o2 + 1] = p1 / zs; out[o2 + 2] = p2;
    }
}

// ---------------------------------------------------------------- per-batch finale
__global__ __launch_bounds__(256) void k_final(const float* __restrict__ vert,
                                               const float* __restrict__ pb,
                                               const int* __restrict__ lmk,
                                               const int* __restrict__ mlmk,
                                               float* __restrict__ out) {
    const int b   = blockIdx.x;
    const int tid = threadIdx.x;
    __shared__ float red[6][256];
    const float* row = vert + (size_t)b * N2_;
    float l0 = 0.f, l1 = 0.f, l2 = 0.f, r0 = 0.f, r1 = 0.f, r2 = 0.f;
    for (int i = tid; i < 2 * NEYE_ * 3; i += 256) {
        float v = row[LE0_ * 3 + i];
        int c = i % 3;
        if (i < NEYE_ * 3) {
            if (c == 0) l0 += v; else if (c == 1) l1 += v; else l2 += v;
        } else {
            if (c == 0) r0 += v; else if (c == 1) r1 += v; else r2 += v;
        }
    }
    red[0][tid] = l0; red[1][tid] = l1; red[2][tid] = l2;
    red[3][tid] = r0; red[4][tid] = r1; red[5][tid] = r2;
    __syncthreads();
    for (int off = 128; off > 0; off >>= 1) {
        if (tid < off) {
#pragma unroll
            for (int q = 0; q < 6; ++q) red[q][tid] += red[q][tid + off];
        }
        __syncthreads();
    }
    if (tid < 204) {
        int j = tid / 3, c = tid % 3;
        int vi = mlmk[j];
        out[((size_t)b * ROWS_ + 7000 + j) * 3 + c] = row[(size_t)vi * 3 + c];
    }
    if (tid == 0) {
        float lc[3], rc[3];
        const float invn = 1.0f / (float)NEYE_;
#pragma unroll
        for (int c = 0; c < 3; ++c) { lc[c] = red[c][0] * invn; rc[c] = red[3 + c][0] * invn; }
        int i4a = lmk[19], i4b = lmk[22], i4c = lmk[25], i4d = lmk[28];
        int i2a = lmk[14], i2b = lmk[18];
        float fc[3];
#pragma unroll
        for (int c = 0; c < 3; ++c) {
            float m4 = (row[i4a * 3 + c] + row[i4b * 3 + c] +
                        row[i4c * 3 + c] + row[i4d * 3 + c]) * 0.25f;
            float m2 = (row[i2a * 3 + c] + row[i2b * 3 + c]) * 0.5f;
            fc[c] = (m4 + m2) * 0.5f;
        }
        const float* p = pb + b * PB_STRIDE;
        float lg[3] = {p[16], p[17], p[18]};
        float rg[3] = {p[19], p[20], p[21]};
        float cr[3] = {rg[1] * lg[2] - rg[2] * lg[1],
                       rg[2] * lg[0] - rg[0] * lg[2],
                       rg[0] * lg[1] - rg[1] * lg[0]};
        float A[3][3], rhs[3];
#pragma unroll
        for (int i = 0; i < 3; ++i) {
            A[i][0] = lg[i]; A[i][1] = -rg[i]; A[i][2] = cr[i];
            rhs[i] = rc[i] - lc[i];
        }
        for (int k = 0; k < 3; ++k) {
            int mrow = k; float mv = fabsf(A[k][k]);
            for (int i = k + 1; i < 3; ++i) {
                float av = fabsf(A[i][k]);
                if (av > mv) { mv = av; mrow = i; }
            }
            if (mrow != k) {
                for (int j = 0; j < 3; ++j) { float t = A[k][j]; A[k][j] = A[mrow][j]; A[mrow][j] = t; }
                float t = rhs[k]; rhs[k] = rhs[mrow]; rhs[mrow] = t;
            }
            float inv = 1.0f / A[k][k];
            for (int i = k + 1; i < 3; ++i) {
                float f = A[i][k] * inv;
                for (int j = k; j < 3; ++j) A[i][j] -= f * A[k][j];
                rhs[i] -= f * rhs[k];
            }
        }
        float sol2 = rhs[2] / A[2][2];
        float sol1 = (rhs[1] - A[1][2] * sol2) / A[1][1];
        float sol0 = (rhs[0] - A[0][1] * sol1 - A[0][2] * sol2) / A[0][0];
        float gpl[3], gpr[3], gpm[3];
#pragma unroll
        for (int c = 0; c < 3; ++c) {
            gpl[c] = lc[c] + sol0 * lg[c];
            gpr[c] = rc[c] + sol1 * rg[c];
            gpm[c] = (gpl[c] + gpr[c]) * 0.5f;
        }
        float d0 = gpl[0] - gpr[0], d1 = gpl[1] - gpr[1], d2 = gpl[2] - gpr[2];
        float dist = sqrtf(d0 * d0 + d1 * d1 + d2 * d2);
        float* o = out + ((size_t)b * ROWS_ + 7068) * 3;
#pragma unroll
        for (int c = 0; c < 3; ++c) {
            o[0 * 3 + c]  = lc[c];
            o[1 * 3 + c]  = rc[c];
            o[2 * 3 + c]  = fc[c];
            o[3 * 3 + c]  = gpl[c];
            o[4 * 3 + c]  = gpr[c];
            o[5 * 3 + c]  = gpm[c];
            o[6 * 3 + c]  = lc[c] + lg[c] * 1000.0f;
            o[7 * 3 + c]  = rc[c] + rg[c] * 1000.0f;
            o[8 * 3 + c]  = lg[c];
            o[9 * 3 + c]  = rg[c];
            o[10 * 3 + c] = dist;
        }
    }
}

// ---------------------------------------------------------------- launcher
extern "C" void kernel_launch(void* const* d_in, const int* in_sizes, int n_in,
                              void* d_out, int out_size, void* d_ws, size_t ws_size,
                              hipStream_t stream) {
    const float* x    = (const float*)d_in[0];
    const float* W    = (const float*)d_in[1];
    const float* eb   = (const float*)d_in[2];
    const float* vt   = (const float*)d_in[3];
    const float* sb   = (const float*)d_in[4];
    const float* cam  = (const float*)d_in[5];
    const int*   lmk  = (const int*)d_in[6];
    const int*   mlmk = (const int*)d_in[7];
    float* out = (float*)d_out;
    float* ws  = (float*)d_ws;
    float* latent = ws + WS_LATENT;
    float* vert0  = ws + WS_VERT0;
    float* vert   = ws + WS_VERT;
    float* pb     = ws + WS_PB;

    k_init_latent<<<139, 256, 0, stream>>>(eb, latent);
    k_gemm<<<dim3(9, 147), 256, 0, stream>>>(x, W, latent);
    k_shape<<<236, 256, 0, stream>>>(latent, sb, vt, vert0);
    k_stats<<<64, 256, 0, stream>>>(vert0, latent, pb);
    k_transform<<<dim3(20, 64), 256, 0, stream>>>(vert0, pb, cam, vert, out);
    k_final<<<64, 256, 0, stream>>>(vert, pb, lmk, mlmk, out);
}

// Round 4
// 574.127 us; speedup vs baseline: 1.1638x; 1.0450x over previous
//
#include <hip/hip_runtime.h>
#include <hip/hip_bf16.h>
#include <math.h>

#define B_    64
#define V_    5023
#define VM_   3500
#define LAT_  556
#define DIN_  150528
#define NS_   400
#define N2_   15069        // V_*3
#define ROWS_ 7079         // per-batch output rows
#define LE0_  3931
#define NEYE_ 546

#define KC_   1024         // K per block (147 chunks)
#define KS_   32           // K per subchunk (one MFMA k-step)
#define NSUB_ (KC_/KS_)
#define NT_   7            // compacted n-tiles (cols 0..384 + {384..400,544..556})
#define SDW_  18           // Wt row stride in dwords (36 f16: 32 + pad 4)
#define XSC_  64.0f
#define WSC_  4096.0f
#define OSC_  (1.0f/262144.0f)   // 2^-18

// ws layout (float offsets)
#define WS_LATENT 0
#define WS_VERT0  35584
#define WS_VERT   1000000
#define WS_PB     1964416
#define PB_STRIDE 32

typedef _Float16 f16x8 __attribute__((ext_vector_type(8)));
typedef float    f32x4 __attribute__((ext_vector_type(4)));

union F16x8 { f16x8 v; unsigned int u[4]; _Float16 h[8]; };

static __device__ inline unsigned int packh(_Float16 a, _Float16 b) {
    union { _Float16 h; unsigned short u; } ca, cb;
    ca.h = a; cb.h = b;
    return (unsigned int)ca.u | ((unsigned int)cb.u << 16);
}

// compacted-column map: tile t, quad q (0..15) -> global quad index or -1.
// Output consumes only latent cols [0,400) and [545,556): skip quads 100..135.
static __device__ inline int quad_map(int t, int q) {
    if (t < 6) return t * 16 + q;        // cols 0..384
    if (q < 4) return 96 + q;            // cols 384..400
    if (q < 7) return 132 + q;           // quads 136..138 = cols 544..556
    return -1;
}

// ---------------------------------------------------------------- init latent
__global__ void k_init_latent(const float* __restrict__ enc_b,
                              float* __restrict__ latent) {
    int i = blockIdx.x * 256 + threadIdx.x;
    if (i < B_ * LAT_) latent[i] = enc_b[i % LAT_];
}

// ---------------------------------------------------------------- big GEMM (MFMA f16-split)
// latent[b][n] += sum_k x[b][k] * W[k][n]   (only needed n-columns)
// grid (7 compacted n-tiles x 147 k-chunks), 256 threads = 4 waves in 2x2.
// Precision: x = xhi + xlo, W = whi + wlo in f16 (scaled); 3 MFMA terms.
__global__ __launch_bounds__(256) void k_gemm(const float* __restrict__ x,
                                              const float* __restrict__ W,
                                              float* __restrict__ latent) {
    // Wt[dbuf][hi/lo][n_local*SDW_ + k/2] : k-pair packed per dword, [n][k] layout
    __shared__ __align__(16) unsigned int wt[2][2][64 * SDW_];
    const int tid = threadIdx.x;
    const int nt  = blockIdx.x;          // compacted n-tile
    const int k0  = blockIdx.y * KC_;
    // staging map: thread handles k-pair (2*skp, 2*skp+1) x 4 cols
    const int sq   = tid & 15;           // col quad
    const int skp  = tid >> 4;           // k-pair index 0..15
    const int gq   = quad_map(nt, sq);
    const bool svalid = gq >= 0;
    const int scol = svalid ? gq * 4 : 0;
    // wave / fragment map: wave w in 2x2 (wr = rows half, wc = cols half)
    const int lane = tid & 63;
    const int w    = tid >> 6;
    const int wr   = w >> 1;
    const int wc   = w & 1;
    const int c16  = lane & 15;
    const int g    = lane >> 4;

    f32x4 acc[2][2] = {};
    float4 wv0, wv1, xc0, xc1, xc2, xc3;
    {   // prologue: load W + x tiles for s=0
        const float* wp = W + (size_t)(k0 + 2 * skp) * LAT_ + scol;
        wv0 = svalid ? *(const float4*)wp : make_float4(0.f, 0.f, 0.f, 0.f);
        wv1 = svalid ? *(const float4*)(wp + LAT_) : make_float4(0.f, 0.f, 0.f, 0.f);
        const float* xp0 = x + (size_t)(32 * wr + c16) * DIN_ + k0 + 8 * g;
        const float* xp1 = xp0 + (size_t)16 * DIN_;
        xc0 = *(const float4*)xp0; xc1 = *(const float4*)(xp0 + 4);
        xc2 = *(const float4*)xp1; xc3 = *(const float4*)(xp1 + 4);
    }
    for (int s = 0; s < NSUB_; ++s) {
        const int db = s & 1;
        {   // convert + transpose-write current W tile into LDS
            float v0[4] = {wv0.x, wv0.y, wv0.z, wv0.w};
            float v1[4] = {wv1.x, wv1.y, wv1.z, wv1.w};
#pragma unroll
            for (int c = 0; c < 4; ++c) {
                float a = v0[c] * WSC_, b = v1[c] * WSC_;
                _Float16 h0 = (_Float16)a, h1 = (_Float16)b;
                _Float16 l0 = (_Float16)(a - (float)h0);
                _Float16 l1 = (_Float16)(b - (float)h1);
                wt[db][0][(sq * 4 + c) * SDW_ + skp] = packh(h0, h1);
                wt[db][1][(sq * 4 + c) * SDW_ + skp] = packh(l0, l1);
            }
        }
        // convert current x regs -> A fragments
        F16x8 ahi[2], alo[2];
        {
            float av0[8] = {xc0.x, xc0.y, xc0.z, xc0.w, xc1.x, xc1.y, xc1.z, xc1.w};
            float av1[8] = {xc2.x, xc2.y, xc2.z, xc2.w, xc3.x, xc3.y, xc3.z, xc3.w};
#pragma unroll
            for (int j = 0; j < 8; ++j) {
                float sv = av0[j] * XSC_;
                _Float16 h = (_Float16)sv;
                ahi[0].h[j] = h;
                alo[0].h[j] = (_Float16)(sv - (float)h);
                float sw = av1[j] * XSC_;
                _Float16 h2 = (_Float16)sw;
                ahi[1].h[j] = h2;
                alo[1].h[j] = (_Float16)(sw - (float)h2);
            }
        }
        __syncthreads();   // wt[db] ready; prior reads of wt[db^1] drained (lgkmcnt)
        // issue next-tile prefetch AFTER the barrier so the loads fly across
        // the LDS-read + MFMA phase (pre-barrier issue would be drained by the
        // compiler's vmcnt(0)-before-s_barrier).
        if (s + 1 < NSUB_) {
            const int kb = k0 + (s + 1) * KS_;
            const float* wp = W + (size_t)(kb + 2 * skp) * LAT_ + scol;
            wv0 = svalid ? *(const float4*)wp : make_float4(0.f, 0.f, 0.f, 0.f);
            wv1 = svalid ? *(const float4*)(wp + LAT_) : make_float4(0.f, 0.f, 0.f, 0.f);
            const float* xp0 = x + (size_t)(32 * wr + c16) * DIN_ + kb + 8 * g;
            const float* xp1 = xp0 + (size_t)16 * DIN_;
            xc0 = *(const float4*)xp0; xc1 = *(const float4*)(xp0 + 4);
            xc2 = *(const float4*)xp1; xc3 = *(const float4*)(xp1 + 4);
        }
        // B fragments from LDS + 12 MFMA
#pragma unroll
        for (int cf = 0; cf < 2; ++cf) {
            const int nl = 32 * wc + 16 * cf + c16;
            const unsigned int* ph = &wt[db][0][nl * SDW_ + 4 * g];
            const unsigned int* pl = &wt[db][1][nl * SDW_ + 4 * g];
            F16x8 bh, bl;
            uint2 t0 = *(const uint2*)ph;
            uint2 t1 = *(const uint2*)(ph + 2);
            bh.u[0] = t0.x; bh.u[1] = t0.y; bh.u[2] = t1.x; bh.u[3] = t1.y;
            uint2 u0 = *(const uint2*)pl;
            uint2 u1 = *(const uint2*)(pl + 2);
            bl.u[0] = u0.x; bl.u[1] = u0.y; bl.u[2] = u1.x; bl.u[3] = u1.y;
#pragma unroll
            for (int rf = 0; rf < 2; ++rf) {
                acc[rf][cf] = __builtin_amdgcn_mfma_f32_16x16x32_f16(ahi[rf].v, bh.v, acc[rf][cf], 0, 0, 0);
                acc[rf][cf] = __builtin_amdgcn_mfma_f32_16x16x32_f16(ahi[rf].v, bl.v, acc[rf][cf], 0, 0, 0);
                acc[rf][cf] = __builtin_amdgcn_mfma_f32_16x16x32_f16(alo[rf].v, bh.v, acc[rf][cf], 0, 0, 0);
            }
        }
    }
    // epilogue: C/D layout col=lane&15, row=(lane>>4)*4+i; map local->actual col
#pragma unroll
    for (int rf = 0; rf < 2; ++rf)
#pragma unroll
        for (int cf = 0; cf < 2; ++cf) {
            const int cl = 32 * wc + 16 * cf + c16;   // local col 0..63
            const int cgq = quad_map(nt, cl >> 2);
            if (cgq < 0) continue;
            const int col = cgq * 4 + (cl & 3);
#pragma unroll
            for (int i = 0; i < 4; ++i) {
                int row = 32 * wr + 16 * rf + 4 * g + i;   // batch
                atomicAdd(&latent[row * LAT_ + col], acc[rf][cf][i] * OSC_);
            }
        }
}

// ---------------------------------------------------------------- shape GEMM
// vert0[b][n] = vt[n] + sum_s latent[b][s] * sb[s][n],  n = v*3+c
__global__ __launch_bounds__(256) void k_shape(const float* __restrict__ latent,
                                               const float* __restrict__ sb,
                                               const float* __restrict__ vt,
                                               float* __restrict__ vert0) {
    __shared__ float ps[16][64];    // [ss][b]
    __shared__ float bs[16][64];    // [ss][n]
    const int n0  = blockIdx.x * 64;
    const int tid = threadIdx.x;
    const int tb  = tid >> 4;
    const int tn  = tid & 15;
    const int lb  = tid >> 2;
    const int ls4 = (tid & 3) << 2;
    const int wss = tid >> 4;
    const int wn4 = (tid & 15) << 2;
    float acc[4][4];
#pragma unroll
    for (int j = 0; j < 4; ++j) {
        int nn = n0 + (tn << 2) + j;
        float v = (nn < N2_) ? vt[nn] : 0.f;
#pragma unroll
        for (int i = 0; i < 4; ++i) acc[i][j] = v;
    }
    for (int st = 0; st < NS_; st += 16) {
        float4 pv = *(const float4*)(latent + lb * LAT_ + st + ls4);
        float wv[4];
        int nn0 = n0 + wn4;
        if (nn0 + 3 < N2_) {
            float4 t = *(const float4*)(sb + (size_t)(st + wss) * N2_ + nn0);
            wv[0] = t.x; wv[1] = t.y; wv[2] = t.z; wv[3] = t.w;
        } else {
#pragma unroll
            for (int j = 0; j < 4; ++j) {
                int nn = nn0 + j;
                wv[j] = (nn < N2_) ? sb[(size_t)(st + wss) * N2_ + nn] : 0.f;
            }
        }
        __syncthreads();
        ps[ls4 + 0][lb] = pv.x;
        ps[ls4 + 1][lb] = pv.y;
        ps[ls4 + 2][lb] = pv.z;
        ps[ls4 + 3][lb] = pv.w;
#pragma unroll
        for (int j = 0; j < 4; ++j) bs[wss][wn4 + j] = wv[j];
        __syncthreads();
#pragma unroll
        for (int ss = 0; ss < 16; ++ss) {
            float4 av = *(const float4*)&ps[ss][tb << 2];
            float4 bv = *(const float4*)&bs[ss][tn << 2];
            float a[4] = {av.x, av.y, av.z, av.w};
            float b4[4] = {bv.x, bv.y, bv.z, bv.w};
#pragma unroll
            for (int i = 0; i < 4; ++i)
#pragma unroll
                for (int j = 0; j < 4; ++j)
                    acc[i][j] = fmaf(a[i], b4[j], acc[i][j]);
        }
    }
#pragma unroll
    for (int i = 0; i < 4; ++i) {
#pragma unroll
        for (int j = 0; j < 4; ++j) {
            int nn = n0 + (tn << 2) + j;
            if (nn < N2_) vert0[(size_t)((tb << 2) + i) * N2_ + nn] = acc[i][j];
        }
    }
}

// ---------------------------------------------------------------- helpers
__device__ inline void axis_angle(const float aa0, const float aa1, const float aa2,
                                  float R[9]) {
    float th  = sqrtf(aa0 * aa0 + aa1 * aa1 + aa2 * aa2);
    float inv = 1.0f / fmaxf(th, 1e-8f);
    float v0 = aa0 * inv, v1 = aa1 * inv, v2 = aa2 * inv;
    float s = sinf(th), c = cosf(th);
    float K[9] = {0.f, -v2, v1, v2, 0.f, -v0, -v1, v0, 0.f};
    float KK[9];
#pragma unroll
    for (int i = 0; i < 3; ++i)
#pragma unroll
        for (int j = 0; j < 3; ++j)
            KK[i * 3 + j] = K[i * 3 + 0] * K[0 * 3 + j] +
                            K[i * 3 + 1] * K[1 * 3 + j] +
                            K[i * 3 + 2] * K[2 * 3 + j];
    float omc = 1.0f - c;
#pragma unroll
    for (int i = 0; i < 9; ++i) R[i] = s * K[i] + omc * KK[i];
    R[0] += 1.f; R[4] += 1.f; R[8] += 1.f;
}

// ---------------------------------------------------------------- per-batch stats
__global__ __launch_bounds__(256) void k_stats(const float* __restrict__ vert0,
                                               const float* __restrict__ latent,
                                               float* __restrict__ pb) {
    const int b   = blockIdx.x;
    const int tid = threadIdx.x;
    __shared__ float red[3][256];
    float s0 = 0.f, s1 = 0.f, s2 = 0.f;
    const float* row = vert0 + (size_t)b * N2_;
    for (int i = tid; i < N2_; i += 256) {
        float v = row[i];
        int c = i % 3;
        if (c == 0) s0 += v; else if (c == 1) s1 += v; else s2 += v;
    }
    red[0][tid] = s0; red[1][tid] = s1; red[2][tid] = s2;
    __syncthreads();
    for (int off = 128; off > 0; off >>= 1) {
        if (tid < off) {
            red[0][tid] += red[0][tid + off];
            red[1][tid] += red[1][tid + off];
            red[2][tid] += red[2][tid + off];
        }
        __syncthreads();
    }
    if (tid == 0) {
        float* p = pb + b * PB_STRIDE;
        p[0] = red[0][0] / (float)V_;
        p[1] = red[1][0] / (float)V_;
        p[2] = red[2][0] / (float)V_;
        const float* lat = latent + b * LAT_;
        float R[9];
        axis_angle(lat[545], lat[546], lat[547], R);
#pragma unroll
        for (int i = 0; i < 9; ++i) p[3 + i] = R[i];
        p[12] = lat[551] + 1.0f;
        p[13] = lat[548]; p[14] = lat[549]; p[15] = lat[550];
        float Rl[9], Rr[9];
        axis_angle(lat[552], lat[553], 0.f, Rl);
        axis_angle(lat[554], lat[555], 0.f, Rr);
        p[16] = -Rl[6]; p[17] = -Rl[7]; p[18] = -Rl[8];
        p[19] = -Rr[6]; p[20] = -Rr[7]; p[21] = -Rr[8];
    }
}

// ---------------------------------------------------------------- transform + project
__global__ __launch_bounds__(256) void k_transform(const float* __restrict__ vert0,
                                                   const float* __restrict__ pb,
                                                   const float* __restrict__ cam,
                                                   float* __restrict__ vert,
                                                   float* __restrict__ out) {
    const int b = blockIdx.y;
    const int v = blockIdx.x * 256 + threadIdx.x;
    if (v >= V_) return;
    const float* p = pb + b * PB_STRIDE;
    const size_t vo = (size_t)b * N2_ + (size_t)v * 3;
    float w0 = vert0[vo + 0] - p[0];
    float w1 = vert0[vo + 1] - p[1];
    float w2 = vert0[vo + 2] - p[2];
    float sc = p[12];
    float r0 = (w0 * p[3] + w1 * p[6] + w2 * p[9])  * sc + p[13];
    float r1 = (w0 * p[4] + w1 * p[7] + w2 * p[10]) * sc + p[14];
    float r2 = (w0 * p[5] + w1 * p[8] + w2 * p[11]) * sc + p[15];
    vert[vo + 0] = r0; vert[vo + 1] = r1; vert[vo + 2] = r2;
    if (v < VM_) {
        size_t o = ((size_t)b * ROWS_ + v) * 3;
        out[o + 0] = r0; out[o + 1] = r1; out[o + 2] = r2;
        const float* cb = cam + b * 12;
        float p0 = cb[0] * r0 + cb[1] * r1 + cb[2]  * r2 + cb[3];
        float p1 = cb[4] * r0 + cb[5] * r1 + cb[6]  * r2 + cb[7];
        float p2 = cb[8] * r0 + cb[9] * r1 + cb[10] * r2 + cb[11];
        float zs = (p2 >= 0.f ? 1.f : -1.f) * fmaxf(fabsf(p2), 0.001f);
        size_t o2 = ((size_t)b * ROWS_ + VM_ + v) * 3;
        out[o2 + 0] = p0 / zs; out[o2 + 1] = p1 / zs; out[o2 + 2] = p2;
    }
}

// ---------------------------------------------------------------- per-batch finale
__global__ __launch_bounds__(256) void k_final(const float* __restrict__ vert,
                                               const float* __restrict__ pb,
                                               const int* __restrict__ lmk,
                                               const int* __restrict__ mlmk,
                                               float* __restrict__ out) {
    const int b   = blockIdx.x;
    const int tid = threadIdx.x;
    __shared__ float red[6][256];
    const float* row = vert + (size_t)b * N2_;
    float l0 = 0.f, l1 = 0.f, l2 = 0.f, r0 = 0.f, r1 = 0.f, r2 = 0.f;
    for (int i = tid; i < 2 * NEYE_ * 3; i += 256) {
        float v = row[LE0_ * 3 + i];
        int c = i % 3;
        if (i < NEYE_ * 3) {
            if (c == 0) l0 += v; else if (c == 1) l1 += v; else l2 += v;
        } else {
            if (c == 0) r0 += v; else if (c == 1) r1 += v; else r2 += v;
        }
    }
    red[0][tid] = l0; red[1][tid] = l1; red[2][tid] = l2;
    red[3][tid] = r0; red[4][tid] = r1; red[5][tid] = r2;
    __syncthreads();
    for (int off = 128; off > 0; off >>= 1) {
        if (tid < off) {
#pragma unroll
            for (int q = 0; q < 6; ++q) red[q][tid] += red[q][tid + off];
        }
        __syncthreads();
    }
    if (tid < 204) {
        int j = tid / 3, c = tid % 3;
        int vi = mlmk[j];
        out[((size_t)b * ROWS_ + 7000 + j) * 3 + c] = row[(size_t)vi * 3 + c];
    }
    if (tid == 0) {
        float lc[3], rc[3];
        const float invn = 1.0f / (float)NEYE_;
#pragma unroll
        for (int c = 0; c < 3; ++c) { lc[c] = red[c][0] * invn; rc[c] = red[3 + c][0] * invn; }
        int i4a = lmk[19], i4b = lmk[22], i4c = lmk[25], i4d = lmk[28];
        int i2a = lmk[14], i2b = lmk[18];
        float fc[3];
#pragma unroll
        for (int c = 0; c < 3; ++c) {
            float m4 = (row[i4a * 3 + c] + row[i4b * 3 + c] +
                        row[i4c * 3 + c] + row[i4d * 3 + c]) * 0.25f;
            float m2 = (row[i2a * 3 + c] + row[i2b * 3 + c]) * 0.5f;
            fc[c] = (m4 + m2) * 0.5f;
        }
        const float* p = pb + b * PB_STRIDE;
        float lg[3] = {p[16], p[17], p[18]};
        float rg[3] = {p[19], p[20], p[21]};
        float cr[3] = {rg[1] * lg[2] - rg[2] * lg[1],
                       rg[2] * lg[0] - rg[0] * lg[2],
                       rg[0] * lg[1] - rg[1] * lg[0]};
        float A[3][3], rhs[3];
#pragma unroll
        for (int i = 0; i < 3; ++i) {
            A[i][0] = lg[i]; A[i][1] = -rg[i]; A[i][2] = cr[i];
            rhs[i] = rc[i] - lc[i];
        }
        for (int k = 0; k < 3; ++k) {
            int mrow = k; float mv = fabsf(A[k][k]);
            for (int i = k + 1; i < 3; ++i) {
                float av = fabsf(A[i][k]);
                if (av > mv) { mv = av; mrow = i; }
            }
            if (mrow != k) {
                for (int j = 0; j < 3; ++j) { float t = A[k][j]; A[k][j] = A[mrow][j]; A[mrow][j] = t; }
                float t = rhs[k]; rhs[k] = rhs[mrow]; rhs[mrow] = t;
            }
            float inv = 1.0f / A[k][k];
            for (int i = k + 1; i < 3; ++i) {
                float f = A[i][k] * inv;
                for (int j = k; j < 3; ++j) A[i][j] -= f * A[k][j];
                rhs[i] -= f * rhs[k];
            }
        }
        float sol2 = rhs[2] / A[2][2];
        float sol1 = (rhs[1] - A[1][2] * sol2) / A[1][1];
        float sol0 = (rhs[0] - A[0][1] * sol1 - A[0][2] * sol2) / A[0][0];
        float gpl[3], gpr[3], gpm[3];
#pragma unroll
        for (int c = 0; c < 3; ++c) {
            gpl[c] = lc[c] + sol0 * lg[c];
            gpr[c] = rc[c] + sol1 * rg[c];
            gpm[c] = (gpl[c] + gpr[c]) * 0.5f;
        }
        float d0 = gpl[0] - gpr[0], d1 = gpl[1] - gpr[1], d2 = gpl[2] - gpr[2];
        float dist = sqrtf(d0 * d0 + d1 * d1 + d2 * d2);
        float* o = out + ((size_t)b * ROWS_ + 7068) * 3;
#pragma unroll
        for (int c = 0; c < 3; ++c) {
            o[0 * 3 + c]  = lc[c];
            o[1 * 3 + c]  = rc[c];
            o[2 * 3 + c]  = fc[c];
            o[3 * 3 + c]  = gpl[c];
            o[4 * 3 + c]  = gpr[c];
            o[5 * 3 + c]  = gpm[c];
            o[6 * 3 + c]  = lc[c] + lg[c] * 1000.0f;
            o[7 * 3 + c]  = rc[c] + rg[c] * 1000.0f;
            o[8 * 3 + c]  = lg[c];
            o[9 * 3 + c]  = rg[c];
            o[10 * 3 + c] = dist;
        }
    }
}

// ---------------------------------------------------------------- launcher
extern "C" void kernel_launch(void* const* d_in, const int* in_sizes, int n_in,
                              void* d_out, int out_size, void* d_ws, size_t ws_size,
                              hipStream_t stream) {
    const float* x    = (const float*)d_in[0];
    const float* W    = (const float*)d_in[1];
    const float* eb   = (const float*)d_in[2];
    const float* vt   = (const float*)d_in[3];
    const float* sb   = (const float*)d_in[4];
    const float* cam  = (const float*)d_in[5];
    const int*   lmk  = (const int*)d_in[6];
    const int*   mlmk = (const int*)d_in[7];
    float* out = (float*)d_out;
    float* ws  = (float*)d_ws;
    float* latent = ws + WS_LATENT;
    float* vert0  = ws + WS_VERT0;
    float* vert   = ws + WS_VERT;
    float* pb     = ws + WS_PB;

    k_init_latent<<<139, 256, 0, stream>>>(eb, latent);
    k_gemm<<<dim3(NT_, 147), 256, 0, stream>>>(x, W, latent);
    k_shape<<<236, 256, 0, stream>>>(latent, sb, vt, vert0);
    k_stats<<<64, 256, 0, stream>>>(vert0, latent, pb);
    k_transform<<<dim3(20, 64), 256, 0, stream>>>(vert0, pb, cam, vert, out);
    k_final<<<64, 256, 0, stream>>>(vert, pb, lmk, mlmk, out);
}